// Round 5
// baseline (217.099 us; speedup 1.0000x reference)
//
#include <hip/hip_runtime.h>
#include <hip/hip_bf16.h>

#define B_DIM 8
#define C_DIM 256
#define S_DIM 2304

typedef __attribute__((ext_vector_type(8))) short short8;
typedef __attribute__((ext_vector_type(4))) float floatx4;

__device__ __forceinline__ void barrier_lgkm() {
    asm volatile("s_waitcnt lgkmcnt(0)\n\ts_barrier" ::: "memory");
}

// ---------------------------------------------------------------------------
// Kernel 1 (round-5 rewrite): L2-normalize over C + transpose [B,C,S] f32 ->
// [B,S,C] bf16, fully register-resident values.
//   Block = 256 threads, tile = 64 s x 256 c.
//   Thread t: s-quad sq = (t&15)*4, c-range c0 = (t>>4)*16 .. +15.
//   Read phase: 16x float4 loads along s (lanes 0-15 cover 256 contiguous
//   bytes -> 1KB/wave-instruction vs round-4's 256B scalar pattern).
//   LDS carries ONLY the 16-way ssq reduction (red[16][68]) + invn[64].
// ---------------------------------------------------------------------------
__global__ __launch_bounds__(256) void norm_transpose_kernel(
    const float* __restrict__ src, const float* __restrict__ dst,
    __hip_bfloat16* __restrict__ srcT, __hip_bfloat16* __restrict__ dstT) {
    const int s0 = blockIdx.x * 64;
    const int b  = blockIdx.y;
    const float* in = (blockIdx.z == 0 ? src : dst) + (size_t)b * C_DIM * S_DIM;
    __hip_bfloat16* out = (blockIdx.z == 0 ? srcT : dstT) + (size_t)b * S_DIM * C_DIM;

    __shared__ float red[16][68];   // +4 pad breaks pow-2 row aliasing
    __shared__ float invn[64];

    const int t  = threadIdx.x;
    const int sq = (t & 15) * 4;    // this thread's 4 s-columns (within tile)
    const int c0 = (t >> 4) * 16;   // this thread's 16 contiguous channels

    float va[4][16];                // the 4s x 16c value patch (64 VGPRs)
    float ssq[4] = {0.f, 0.f, 0.f, 0.f};

#pragma unroll
    for (int i = 0; i < 16; ++i) {
        float4 v = *(const float4*)&in[(size_t)(c0 + i) * S_DIM + s0 + sq];
        va[0][i] = v.x; va[1][i] = v.y; va[2][i] = v.z; va[3][i] = v.w;
        ssq[0] += v.x * v.x; ssq[1] += v.y * v.y;
        ssq[2] += v.z * v.z; ssq[3] += v.w * v.w;
    }

    // 16-way cross-thread reduction of ssq per s-column.
    *(float4*)&red[t >> 4][sq] = *(float4*)ssq;
    __syncthreads();
    if (t < 64) {
        float s = 0.f;
#pragma unroll
        for (int g = 0; g < 16; ++g) s += red[g][t];
        invn[t] = rsqrtf(s);
    }
    __syncthreads();

    // Scale + convert + store: per s, 16 bf16 = two 16B chunks, addresses
    // 16B-aligned (c0 multiple of 16).
#pragma unroll
    for (int j = 0; j < 4; ++j) {
        float inv = invn[sq + j];
        union { short8 v[2]; __hip_bfloat16 h[16]; } o;
#pragma unroll
        for (int i = 0; i < 16; ++i)
            o.h[i] = __float2bfloat16(va[j][i] * inv);
        __hip_bfloat16* p = &out[(size_t)(s0 + sq + j) * C_DIM + c0];
        *(short8*)p       = o.v[0];
        *(short8*)(p + 8) = o.v[1];
    }
}

// ---------------------------------------------------------------------------
// Kernel 2: byte-identical to round 4 (best variant; K-loop proven
// insensitive to pipelining across 4 structures — do not touch).
// ---------------------------------------------------------------------------
__global__ __launch_bounds__(256) void gemm_relu_kernel(
    const __hip_bfloat16* __restrict__ At, const __hip_bfloat16* __restrict__ Bt,
    float* __restrict__ out) {
    const int id = blockIdx.x;
    const int b  = id & 7;          // batch -> XCD (id%8 round-robin)
    const int q  = id >> 3;
    const int m0 = (q % 18) * 128;
    const int n0 = (q / 18) * 128;
    const __hip_bfloat16* A  = At + (size_t)b * S_DIM * C_DIM;
    const __hip_bfloat16* Bp = Bt + (size_t)b * S_DIM * C_DIM;

    __shared__ __align__(16) unsigned char smem[33792];
    __hip_bfloat16* stg = (__hip_bfloat16*)smem;
    float* Cs = (float*)smem;

    const int t    = threadIdx.x;
    const int lane = t & 63;
    const int wv   = t >> 6;

    const int fm = lane & 15;
    const int kq = (lane >> 4) << 3;
    const int wr = (wv >> 1) << 6;
    const int wc = (wv & 1) << 6;
    const int rq = (lane >> 4) << 2;

    const int e0   = wv * 1024 + lane * 8;
    const int row0 = e0 >> 5, kc0 = e0 & 31;
    const int e1   = e0 + 512;
    const int row1 = e1 >> 5, kc1 = e1 & 31;

    const __hip_bfloat16* gA0 = A  + (size_t)(m0 + row0) * C_DIM + kc0;
    const __hip_bfloat16* gA1 = A  + (size_t)(m0 + row1) * C_DIM + kc1;
    const __hip_bfloat16* gB0 = Bp + (size_t)(n0 + row0) * C_DIM + kc0;
    const __hip_bfloat16* gB1 = Bp + (size_t)(n0 + row1) * C_DIM + kc1;

    short8 rA0 = *(const short8*)gA0;
    short8 rA1 = *(const short8*)gA1;
    short8 rB0 = *(const short8*)gB0;
    short8 rB1 = *(const short8*)gB1;

    floatx4 acc[4][4] = {};

#pragma unroll
    for (int ki = 0; ki < 8; ++ki) {
        __hip_bfloat16* As = stg + (ki & 1) * 4096;
        __hip_bfloat16* Bs = stg + 8192 + (ki & 1) * 4096;

        *(short8*)(As + e0) = rA0;
        *(short8*)(As + e1) = rA1;
        *(short8*)(Bs + e0) = rB0;
        *(short8*)(Bs + e1) = rB1;

        if (ki < 7) {
            int off = (ki + 1) * 32;
            rA0 = *(const short8*)(gA0 + off);
            rA1 = *(const short8*)(gA1 + off);
            rB0 = *(const short8*)(gB0 + off);
            rB1 = *(const short8*)(gB1 + off);
        }

        barrier_lgkm();

        short8 af[4], bf[4];
#pragma unroll
        for (int i = 0; i < 4; ++i) {
            af[i] = *(const short8*)&As[(wr + i * 16 + fm) * 32 + kq];
            bf[i] = *(const short8*)&Bs[(wc + i * 16 + fm) * 32 + kq];
        }
#pragma unroll
        for (int i = 0; i < 4; ++i)
#pragma unroll
            for (int j = 0; j < 4; ++j)
                acc[i][j] = __builtin_amdgcn_mfma_f32_16x16x32_bf16(af[i], bf[j], acc[i][j], 0, 0, 0);
    }

    float* Cp = out + (size_t)b * S_DIM * S_DIM;
#pragma unroll
    for (int p = 0; p < 2; ++p) {
        __syncthreads();
#pragma unroll
        for (int i2 = 0; i2 < 2; ++i2) {
            int i = 2 * p + i2;
            int slot = (wr >> 1) + i2 * 16 + rq;
#pragma unroll
            for (int j = 0; j < 4; ++j) {
                int col = wc + j * 16 + fm;
#pragma unroll
                for (int r = 0; r < 4; ++r)
                    Cs[(slot + r) * 132 + col] = fmaxf(acc[i][j][r], 0.f);
            }
        }
        __syncthreads();
#pragma unroll
        for (int it = 0; it < 8; ++it) {
            int idx  = it * 256 + t;
            int srow = idx >> 5;
            int c4   = (idx & 31) << 2;
            float4 v = *(const float4*)&Cs[srow * 132 + c4];
            int lrow = 32 * p + (srow & 31) + ((srow >> 5) << 6);
            *(float4*)&Cp[(size_t)(m0 + lrow) * S_DIM + n0 + c4] = v;
        }
    }
}

extern "C" void kernel_launch(void* const* d_in, const int* in_sizes, int n_in,
                              void* d_out, int out_size, void* d_ws, size_t ws_size,
                              hipStream_t stream) {
    const float* src = (const float*)d_in[0];
    const float* dst = (const float*)d_in[1];
    float* out = (float*)d_out;

    __hip_bfloat16* srcT = (__hip_bfloat16*)d_ws;
    __hip_bfloat16* dstT = srcT + (size_t)B_DIM * S_DIM * C_DIM;

    dim3 g1(S_DIM / 64, B_DIM, 2);
    norm_transpose_kernel<<<g1, 256, 0, stream>>>(src, dst, srcT, dstT);

    gemm_relu_kernel<<<dim3(B_DIM * 18 * 18), 256, 0, stream>>>(srcT, dstT, out);
}